// Round 8
// baseline (178.225 us; speedup 1.0000x reference)
//
#include <hip/hip_runtime.h>
#include <math.h>

#define NB 8      // NUM_BATCHES
#define C  256    // channels
#define CR 64     // C / r

#define POOL_BLOCKS  512
#define SCALE_BLOCKS 2048

typedef float vf4 __attribute__((ext_vector_type(4)));

// ---------------------------------------------------------------------------
// Kernel 1: per-batch partial sums + counts. One wave per 4-row group
// (4 KB contiguous streaming; one int4 load fetches the 4 bids).
// Wave-uniform bid -> branch-free predicated FMA into vf4 acc[8] (VGPRs).
// x loads are CACHED (install x in L3 for scale's chunk-reversed re-read).
// LDS merge once at the end; per-block partials out (no atomics, no memset).
// ---------------------------------------------------------------------------
__global__ __launch_bounds__(256) void pool_kernel(
    const float* __restrict__ x,         // [N, 256]
    const int*   __restrict__ bids,      // [N]
    float*       __restrict__ partials,  // [POOL_BLOCKS][2048]
    float*       __restrict__ cpart,     // [POOL_BLOCKS][8]
    int N)
{
    __shared__ float lsum[4][NB][C];   // 32 KB
    __shared__ float lcnt[4][NB];

    const int tid  = threadIdx.x;
    const int wid  = tid >> 6;
    const int lane = tid & 63;

    vf4   acc[NB];
    float cnt[NB];
    #pragma unroll
    for (int b = 0; b < NB; ++b) { acc[b] = (vf4){0.f,0.f,0.f,0.f}; cnt[b] = 0.f; }

    const int gwave   = blockIdx.x * 4 + wid;
    const int totw    = POOL_BLOCKS * 4;
    const int ngroups = N >> 2;

    for (int g = gwave; g < ngroups; g += totw) {
        const size_t r0 = (size_t)g * 4;
        const int4 bb = *((const int4*)(bids + r0));     // 4 bids, 1 load
        const int b0 = __builtin_amdgcn_readfirstlane(bb.x);
        const int b1 = __builtin_amdgcn_readfirstlane(bb.y);
        const int b2 = __builtin_amdgcn_readfirstlane(bb.z);
        const int b3 = __builtin_amdgcn_readfirstlane(bb.w);
        const vf4 v0 = ((const vf4*)(x + (r0 + 0) * C))[lane];   // cached
        const vf4 v1 = ((const vf4*)(x + (r0 + 1) * C))[lane];
        const vf4 v2 = ((const vf4*)(x + (r0 + 2) * C))[lane];
        const vf4 v3 = ((const vf4*)(x + (r0 + 3) * C))[lane];
        #pragma unroll
        for (int b = 0; b < NB; ++b) {
            const float m0 = (b0 == b) ? 1.f : 0.f;
            const float m1 = (b1 == b) ? 1.f : 0.f;
            const float m2 = (b2 == b) ? 1.f : 0.f;
            const float m3 = (b3 == b) ? 1.f : 0.f;
            acc[b] += v0 * m0;
            acc[b] += v1 * m1;
            acc[b] += v2 * m2;
            acc[b] += v3 * m3;
            cnt[b] += m0 + m1 + m2 + m3;
        }
    }
    // leftover rows if N % 4 != 0 (none at N=262144) — wave 0 handles them
    if (gwave == 0) {
        for (int row = ngroups * 4; row < N; ++row) {
            const int bb = __builtin_amdgcn_readfirstlane(bids[row]);
            const vf4 v = ((const vf4*)(x + (size_t)row * C))[lane];
            #pragma unroll
            for (int b = 0; b < NB; ++b) {
                const float m = (bb == b) ? 1.f : 0.f;
                acc[b] += v * m;
                cnt[b] += m;
            }
        }
    }

    // one conflict-free b128 LDS write per batch per lane
    #pragma unroll
    for (int b = 0; b < NB; ++b)
        ((vf4*)&lsum[wid][b][0])[lane] = acc[b];
    if (lane == 0) {
        #pragma unroll
        for (int b = 0; b < NB; ++b) lcnt[wid][b] = cnt[b];
    }
    __syncthreads();

    float* pout = partials + (size_t)blockIdx.x * (NB * C);
    for (int i = tid; i < NB * C; i += 256)
        pout[i] = lsum[0][0][i] + lsum[1][0][i] + lsum[2][0][i] + lsum[3][0][i];
    if (tid < NB)
        cpart[blockIdx.x * NB + tid] =
            lcnt[0][tid] + lcnt[1][tid] + lcnt[2][tid] + lcnt[3][tid];
}

// ---------------------------------------------------------------------------
// Kernel 2: tree-reduce the per-block partials. 64 blocks: blockIdx = jp*8+jo;
// block sums PR partial rows over its 256-col chunk (coalesced 1 KB reads).
// jo==0 blocks also reduce the count partials.
// ---------------------------------------------------------------------------
__global__ __launch_bounds__(256) void reduce_kernel(
    const float* __restrict__ partials,  // [POOL_BLOCKS][2048]
    const float* __restrict__ cpart,     // [POOL_BLOCKS][8]
    float*       __restrict__ partial2,  // [8][2048]
    float*       __restrict__ c2)        // [8][8]
{
    const int jo  = blockIdx.x & 7;   // column chunk
    const int jp  = blockIdx.x >> 3;  // partial-row chunk
    const int col = jo * 256 + threadIdx.x;
    const int PR  = POOL_BLOCKS / 8;  // 64 rows per jp

    float s = 0.f;
    #pragma unroll 8
    for (int p = 0; p < PR; ++p)
        s += partials[(size_t)(jp * PR + p) * (NB * C) + col];
    partial2[jp * (NB * C) + col] = s;

    if (jo == 0 && threadIdx.x < NB) {
        float c = 0.f;
        for (int p = 0; p < PR; ++p)
            c += cpart[(jp * PR + p) * NB + threadIdx.x];
        c2[jp * NB + threadIdx.x] = c;
    }
}

// ---------------------------------------------------------------------------
// Kernel 3: final reduce + tiny MLP. pooled = sums/max(cnt,1);
// h = relu(pooled@W1+b1); y = sigmoid(h@W2+b2). One block, 256 threads.
// ---------------------------------------------------------------------------
__global__ __launch_bounds__(256) void mlp_kernel(
    const float* __restrict__ partial2,  // [8][2048]
    const float* __restrict__ c2,        // [8][8]
    const float* __restrict__ W1,        // [256][64]
    const float* __restrict__ b1,        // [64]
    const float* __restrict__ W2,        // [64][256]
    const float* __restrict__ b2,        // [256]
    float*       __restrict__ y)         // [8][256] out
{
    __shared__ float pooled[NB][C];
    __shared__ float h[NB][CR];
    __shared__ float cnts[NB];
    const int tid = threadIdx.x;

    if (tid < NB) {
        float c = 0.f;
        #pragma unroll
        for (int j = 0; j < 8; ++j) c += c2[j * NB + tid];
        cnts[tid] = fmaxf(c, 1.f);
    }
    __syncthreads();

    for (int i = tid; i < NB * C; i += 256) {
        float s = 0.f;
        #pragma unroll
        for (int j = 0; j < 8; ++j) s += partial2[j * (NB * C) + i];
        (&pooled[0][0])[i] = s / cnts[i >> 8];
    }
    __syncthreads();

    // h: 8*64 = 512 outputs, 2 per thread
    for (int o = tid; o < NB * CR; o += 256) {
        const int b = o >> 6, j = o & 63;
        float acc = b1[j];
        #pragma unroll 4
        for (int k = 0; k < C; ++k) acc = fmaf(pooled[b][k], W1[k * CR + j], acc);
        (&h[0][0])[o] = fmaxf(acc, 0.f);
    }
    __syncthreads();

    // y: 8*256 = 2048 outputs, 8 per thread
    for (int o = tid; o < NB * C; o += 256) {
        const int b = o >> 8, j = o & 255;
        float acc = b2[j];
        #pragma unroll
        for (int k = 0; k < CR; ++k) acc = fmaf(h[b][k], W2[k * C + j], acc);
        y[o] = 1.f / (1.f + __expf(-acc));
    }
}

// ---------------------------------------------------------------------------
// Kernel 4: out[row,:] = y[bids[row],:] * x[row,:].
// CHUNK-REVERSED, locally-forward: each block owns one contiguous 32-group
// (128-row, 128 KB) slab; block 0 takes the LAST slab (the x rows pool read
// most recently -> hottest in L3), walking slabs backwards while every wave
// streams forward within its slab (keeps DRAM page locality — R4's full
// reversal broke that). x loads CACHED to exploit L3; out stores NT so the
// write stream doesn't evict x.
// ---------------------------------------------------------------------------
__global__ __launch_bounds__(256) void scale_kernel(
    const float* __restrict__ x,     // [N, 256]
    const int*   __restrict__ bids,  // [N]
    const float* __restrict__ y,     // [8][256]
    float*       __restrict__ out,   // [N, 256]
    int N)
{
    __shared__ float ly[NB][C];      // 8 KB
    const int tid = threadIdx.x;
    for (int i = tid; i < NB * C; i += 256) (&ly[0][0])[i] = y[i];
    __syncthreads();

    const int wid  = tid >> 6;
    const int lane = tid & 63;
    const int ngroups = N >> 2;
    const int gpb = (ngroups + SCALE_BLOCKS - 1) / SCALE_BLOCKS;  // 32
    const int gpw = (gpb + 3) / 4;                                // 8
    const int slab = SCALE_BLOCKS - 1 - blockIdx.x;               // reversed
    const int gstart = slab * gpb + wid * gpw;
    const int gend   = min(min(gstart + gpw, slab * gpb + gpb), ngroups);

    for (int g = gstart; g < gend; ++g) {
        const size_t r0 = (size_t)g * 4;
        const int4 bb = *((const int4*)(bids + r0));     // 4 bids, 1 load
        const int b0 = __builtin_amdgcn_readfirstlane(bb.x);
        const int b1 = __builtin_amdgcn_readfirstlane(bb.y);
        const int b2 = __builtin_amdgcn_readfirstlane(bb.z);
        const int b3 = __builtin_amdgcn_readfirstlane(bb.w);
        const vf4 v0 = ((const vf4*)(x + (r0 + 0) * C))[lane];   // cached
        const vf4 v1 = ((const vf4*)(x + (r0 + 1) * C))[lane];
        const vf4 v2 = ((const vf4*)(x + (r0 + 2) * C))[lane];
        const vf4 v3 = ((const vf4*)(x + (r0 + 3) * C))[lane];
        const vf4 g0 = ((const vf4*)&ly[b0][0])[lane];
        const vf4 g1 = ((const vf4*)&ly[b1][0])[lane];
        const vf4 g2 = ((const vf4*)&ly[b2][0])[lane];
        const vf4 g3 = ((const vf4*)&ly[b3][0])[lane];
        __builtin_nontemporal_store(v0 * g0, ((vf4*)(out + (r0 + 0) * C)) + lane);
        __builtin_nontemporal_store(v1 * g1, ((vf4*)(out + (r0 + 1) * C)) + lane);
        __builtin_nontemporal_store(v2 * g2, ((vf4*)(out + (r0 + 2) * C)) + lane);
        __builtin_nontemporal_store(v3 * g3, ((vf4*)(out + (r0 + 3) * C)) + lane);
    }
    // tail rows (N % 4 != 0; none at N=262144) — handled by the first-launched
    // block (slab 0 owner is the LAST block; use blockIdx 0 / highest slab)
    if (blockIdx.x == 0 && wid == 0) {
        for (int row = ngroups * 4; row < N; ++row) {
            const int bb = __builtin_amdgcn_readfirstlane(bids[row]);
            const vf4 v  = ((const vf4*)(x + (size_t)row * C))[lane];
            const vf4 gg = ((const vf4*)&ly[bb][0])[lane];
            ((vf4*)(out + (size_t)row * C))[lane] = v * gg;
        }
    }
}

extern "C" void kernel_launch(void* const* d_in, const int* in_sizes, int n_in,
                              void* d_out, int out_size, void* d_ws, size_t ws_size,
                              hipStream_t stream)
{
    const float* x    = (const float*)d_in[0];
    const int*   bids = (const int*)  d_in[1];
    const float* W1   = (const float*)d_in[2];
    const float* b1   = (const float*)d_in[3];
    const float* W2   = (const float*)d_in[4];
    const float* b2   = (const float*)d_in[5];
    float* out = (float*)d_out;

    const int N = in_sizes[1];           // 262144

    // ws layout (floats), all regions fully written before read each call:
    // partials[512*2048] | cpart[512*8] | partial2[8*2048] | c2[64] | gy[2048]
    float* partials = (float*)d_ws;
    float* cpart    = partials + POOL_BLOCKS * (NB * C);
    float* partial2 = cpart + POOL_BLOCKS * NB;
    float* c2       = partial2 + 8 * (NB * C);
    float* gy       = c2 + 64;

    pool_kernel  <<<POOL_BLOCKS, 256, 0, stream>>>(x, bids, partials, cpart, N);
    reduce_kernel<<<64, 256, 0, stream>>>(partials, cpart, partial2, c2);
    mlp_kernel   <<<1, 256, 0, stream>>>(partial2, c2, W1, b1, W2, b2, gy);
    scale_kernel <<<SCALE_BLOCKS, 256, 0, stream>>>(x, bids, gy, out, N);
}

// Round 9
// 174.592 us; speedup vs baseline: 1.0208x; 1.0208x over previous
//
#include <hip/hip_runtime.h>
#include <math.h>

#define NB 8      // NUM_BATCHES
#define C  256    // channels
#define CR 64     // C / r

#define POOL_BLOCKS  512
#define SCALE_BLOCKS 2048

typedef float vf4 __attribute__((ext_vector_type(4)));

// ---------------------------------------------------------------------------
// Kernel 1: per-batch partial sums + counts. One wave per 4-row group
// (4 KB contiguous NT streaming; one int4 load fetches the 4 bids).
// Wave-uniform bid -> branch-free predicated FMA into vf4 acc[8] (VGPRs).
// LDS merge once at the end; per-block partials out (no atomics, no memset).
// Memory policy: forward order + NT loads/stores everywhere (R4/R8 proved
// cached/reordered variants lose ~10us; L3 reuse is not exploitable here).
// ---------------------------------------------------------------------------
__global__ __launch_bounds__(256) void pool_kernel(
    const float* __restrict__ x,         // [N, 256]
    const int*   __restrict__ bids,      // [N]
    float*       __restrict__ partials,  // [POOL_BLOCKS][2048]
    float*       __restrict__ cpart,     // [POOL_BLOCKS][8]
    int N)
{
    __shared__ float lsum[4][NB][C];   // 32 KB
    __shared__ float lcnt[4][NB];

    const int tid  = threadIdx.x;
    const int wid  = tid >> 6;
    const int lane = tid & 63;

    vf4   acc[NB];
    float cnt[NB];
    #pragma unroll
    for (int b = 0; b < NB; ++b) { acc[b] = (vf4){0.f,0.f,0.f,0.f}; cnt[b] = 0.f; }

    const int gwave   = blockIdx.x * 4 + wid;
    const int totw    = POOL_BLOCKS * 4;
    const int ngroups = N >> 2;

    for (int g = gwave; g < ngroups; g += totw) {
        const size_t r0 = (size_t)g * 4;
        const int4 bb = *((const int4*)(bids + r0));     // 4 bids, 1 load
        const int b0 = __builtin_amdgcn_readfirstlane(bb.x);
        const int b1 = __builtin_amdgcn_readfirstlane(bb.y);
        const int b2 = __builtin_amdgcn_readfirstlane(bb.z);
        const int b3 = __builtin_amdgcn_readfirstlane(bb.w);
        const vf4 v0 = __builtin_nontemporal_load(((const vf4*)(x + (r0 + 0) * C)) + lane);
        const vf4 v1 = __builtin_nontemporal_load(((const vf4*)(x + (r0 + 1) * C)) + lane);
        const vf4 v2 = __builtin_nontemporal_load(((const vf4*)(x + (r0 + 2) * C)) + lane);
        const vf4 v3 = __builtin_nontemporal_load(((const vf4*)(x + (r0 + 3) * C)) + lane);
        #pragma unroll
        for (int b = 0; b < NB; ++b) {
            const float m0 = (b0 == b) ? 1.f : 0.f;
            const float m1 = (b1 == b) ? 1.f : 0.f;
            const float m2 = (b2 == b) ? 1.f : 0.f;
            const float m3 = (b3 == b) ? 1.f : 0.f;
            acc[b] += v0 * m0;
            acc[b] += v1 * m1;
            acc[b] += v2 * m2;
            acc[b] += v3 * m3;
            cnt[b] += m0 + m1 + m2 + m3;
        }
    }
    // leftover rows if N % 4 != 0 (none at N=262144) — wave 0 handles them
    if (gwave == 0) {
        for (int row = ngroups * 4; row < N; ++row) {
            const int bb = __builtin_amdgcn_readfirstlane(bids[row]);
            const vf4 v = ((const vf4*)(x + (size_t)row * C))[lane];
            #pragma unroll
            for (int b = 0; b < NB; ++b) {
                const float m = (bb == b) ? 1.f : 0.f;
                acc[b] += v * m;
                cnt[b] += m;
            }
        }
    }

    // one conflict-free b128 LDS write per batch per lane
    #pragma unroll
    for (int b = 0; b < NB; ++b)
        ((vf4*)&lsum[wid][b][0])[lane] = acc[b];
    if (lane == 0) {
        #pragma unroll
        for (int b = 0; b < NB; ++b) lcnt[wid][b] = cnt[b];
    }
    __syncthreads();

    float* pout = partials + (size_t)blockIdx.x * (NB * C);
    for (int i = tid; i < NB * C; i += 256)
        pout[i] = lsum[0][0][i] + lsum[1][0][i] + lsum[2][0][i] + lsum[3][0][i];
    if (tid < NB)
        cpart[blockIdx.x * NB + tid] =
            lcnt[0][tid] + lcnt[1][tid] + lcnt[2][tid] + lcnt[3][tid];
}

// ---------------------------------------------------------------------------
// Kernel 2 (merged reduce + MLP): the MLP is PER-BATCH independent, so one
// block per batch (8 blocks, 256 threads). Each block:
//  - tree-reduces its batch's 256-col slice over all POOL_BLOCKS partials
//    (coalesced 1 KB rows, ~512 KB per block),
//  - reduces its batch's count,
//  - computes h[b] = relu(pooled[b]@W1+b1), y[b] = sigmoid(h[b]@W2+b2).
// Replaces the old reduce_kernel + 1-block mlp_kernel (one fewer dispatch,
// 8x more parallel MLP).
// ---------------------------------------------------------------------------
__global__ __launch_bounds__(256) void reduce_mlp_kernel(
    const float* __restrict__ partials,  // [POOL_BLOCKS][2048]
    const float* __restrict__ cpart,     // [POOL_BLOCKS][8]
    const float* __restrict__ W1,        // [256][64]
    const float* __restrict__ b1,        // [64]
    const float* __restrict__ W2,        // [64][256]
    const float* __restrict__ b2,        // [256]
    float*       __restrict__ y)         // [8][256] out
{
    __shared__ float pooled[C];
    __shared__ float h[CR];
    __shared__ float red[256];

    const int b   = blockIdx.x;      // batch
    const int tid = threadIdx.x;     // column

    // column sum over all partial rows (coalesced: 256 consecutive floats/row)
    float s = 0.f;
    #pragma unroll 8
    for (int p = 0; p < POOL_BLOCKS; ++p)
        s += partials[(size_t)p * (NB * C) + b * C + tid];

    // count reduce
    float c = 0.f;
    for (int p = tid; p < POOL_BLOCKS; p += 256) c += cpart[p * NB + b];
    red[tid] = c;
    __syncthreads();
    #pragma unroll
    for (int off = 128; off > 0; off >>= 1) {
        if (tid < off) red[tid] += red[tid + off];
        __syncthreads();
    }
    const float cnt = fmaxf(red[0], 1.f);

    pooled[tid] = s / cnt;
    __syncthreads();

    if (tid < CR) {                              // h: 64 outputs
        float a = b1[tid];
        #pragma unroll 4
        for (int k = 0; k < C; ++k) a = fmaf(pooled[k], W1[k * CR + tid], a);
        h[tid] = fmaxf(a, 0.f);
    }
    __syncthreads();

    {                                            // y: 256 outputs
        float a = b2[tid];
        #pragma unroll
        for (int k = 0; k < CR; ++k) a = fmaf(h[k], W2[k * C + tid], a);
        y[b * C + tid] = 1.f / (1.f + __expf(-a));
    }
}

// ---------------------------------------------------------------------------
// Kernel 3: out[row,:] = y[bids[row],:] * x[row,:]. One wave per 8-row group
// (8 KB contiguous read + 8 KB write, 8 loads in flight), FORWARD order,
// y cached in LDS (uniform bid -> 2-way b128 = free), NT load/store,
// two int4 bid loads per group.
// ---------------------------------------------------------------------------
__global__ __launch_bounds__(256) void scale_kernel(
    const float* __restrict__ x,     // [N, 256]
    const int*   __restrict__ bids,  // [N]
    const float* __restrict__ y,     // [8][256]
    float*       __restrict__ out,   // [N, 256]
    int N)
{
    __shared__ float ly[NB][C];      // 8 KB
    const int tid = threadIdx.x;
    for (int i = tid; i < NB * C; i += 256) (&ly[0][0])[i] = y[i];
    __syncthreads();

    const int wid  = tid >> 6;
    const int lane = tid & 63;
    const int gwave    = blockIdx.x * 4 + wid;
    const int totw     = SCALE_BLOCKS * 4;
    const int ngroups8 = N >> 3;

    for (int g = gwave; g < ngroups8; g += totw) {
        const size_t r0 = (size_t)g * 8;
        const int4 ba = *((const int4*)(bids + r0));
        const int4 bc = *((const int4*)(bids + r0 + 4));
        const int b0 = __builtin_amdgcn_readfirstlane(ba.x);
        const int b1 = __builtin_amdgcn_readfirstlane(ba.y);
        const int b2 = __builtin_amdgcn_readfirstlane(ba.z);
        const int b3 = __builtin_amdgcn_readfirstlane(ba.w);
        const int b4 = __builtin_amdgcn_readfirstlane(bc.x);
        const int b5 = __builtin_amdgcn_readfirstlane(bc.y);
        const int b6 = __builtin_amdgcn_readfirstlane(bc.z);
        const int b7 = __builtin_amdgcn_readfirstlane(bc.w);
        const vf4 v0 = __builtin_nontemporal_load(((const vf4*)(x + (r0 + 0) * C)) + lane);
        const vf4 v1 = __builtin_nontemporal_load(((const vf4*)(x + (r0 + 1) * C)) + lane);
        const vf4 v2 = __builtin_nontemporal_load(((const vf4*)(x + (r0 + 2) * C)) + lane);
        const vf4 v3 = __builtin_nontemporal_load(((const vf4*)(x + (r0 + 3) * C)) + lane);
        const vf4 v4 = __builtin_nontemporal_load(((const vf4*)(x + (r0 + 4) * C)) + lane);
        const vf4 v5 = __builtin_nontemporal_load(((const vf4*)(x + (r0 + 5) * C)) + lane);
        const vf4 v6 = __builtin_nontemporal_load(((const vf4*)(x + (r0 + 6) * C)) + lane);
        const vf4 v7 = __builtin_nontemporal_load(((const vf4*)(x + (r0 + 7) * C)) + lane);
        const vf4 g0 = ((const vf4*)&ly[b0][0])[lane];
        const vf4 g1 = ((const vf4*)&ly[b1][0])[lane];
        const vf4 g2 = ((const vf4*)&ly[b2][0])[lane];
        const vf4 g3 = ((const vf4*)&ly[b3][0])[lane];
        const vf4 g4 = ((const vf4*)&ly[b4][0])[lane];
        const vf4 g5 = ((const vf4*)&ly[b5][0])[lane];
        const vf4 g6 = ((const vf4*)&ly[b6][0])[lane];
        const vf4 g7 = ((const vf4*)&ly[b7][0])[lane];
        __builtin_nontemporal_store(v0 * g0, ((vf4*)(out + (r0 + 0) * C)) + lane);
        __builtin_nontemporal_store(v1 * g1, ((vf4*)(out + (r0 + 1) * C)) + lane);
        __builtin_nontemporal_store(v2 * g2, ((vf4*)(out + (r0 + 2) * C)) + lane);
        __builtin_nontemporal_store(v3 * g3, ((vf4*)(out + (r0 + 3) * C)) + lane);
        __builtin_nontemporal_store(v4 * g4, ((vf4*)(out + (r0 + 4) * C)) + lane);
        __builtin_nontemporal_store(v5 * g5, ((vf4*)(out + (r0 + 5) * C)) + lane);
        __builtin_nontemporal_store(v6 * g6, ((vf4*)(out + (r0 + 6) * C)) + lane);
        __builtin_nontemporal_store(v7 * g7, ((vf4*)(out + (r0 + 7) * C)) + lane);
    }
    if (gwave == 0) {                 // tail rows if N % 8 != 0
        for (int row = ngroups8 * 8; row < N; ++row) {
            const int bb = __builtin_amdgcn_readfirstlane(bids[row]);
            const vf4 v  = ((const vf4*)(x + (size_t)row * C))[lane];
            const vf4 gg = ((const vf4*)&ly[bb][0])[lane];
            ((vf4*)(out + (size_t)row * C))[lane] = v * gg;
        }
    }
}

extern "C" void kernel_launch(void* const* d_in, const int* in_sizes, int n_in,
                              void* d_out, int out_size, void* d_ws, size_t ws_size,
                              hipStream_t stream)
{
    const float* x    = (const float*)d_in[0];
    const int*   bids = (const int*)  d_in[1];
    const float* W1   = (const float*)d_in[2];
    const float* b1   = (const float*)d_in[3];
    const float* W2   = (const float*)d_in[4];
    const float* b2   = (const float*)d_in[5];
    float* out = (float*)d_out;

    const int N = in_sizes[1];           // 262144

    // ws layout (floats), all regions fully written before read each call:
    // partials[512*2048] | cpart[512*8] | gy[2048]
    float* partials = (float*)d_ws;
    float* cpart    = partials + POOL_BLOCKS * (NB * C);
    float* gy       = cpart + POOL_BLOCKS * NB;

    pool_kernel      <<<POOL_BLOCKS, 256, 0, stream>>>(x, bids, partials, cpart, N);
    reduce_mlp_kernel<<<NB, 256, 0, stream>>>(partials, cpart, W1, b1, W2, b2, gy);
    scale_kernel     <<<SCALE_BLOCKS, 256, 0, stream>>>(x, bids, gy, out, N);
}

// Round 10
// 163.542 us; speedup vs baseline: 1.0898x; 1.0676x over previous
//
#include <hip/hip_runtime.h>
#include <math.h>

#define NB 8      // NUM_BATCHES
#define C  256    // channels
#define CR 64     // C / r

#define POOL_BLOCKS  512
#define SCALE_BLOCKS 2048

typedef float vf4 __attribute__((ext_vector_type(4)));

// ---------------------------------------------------------------------------
// Kernel 1: per-batch partial sums + counts. One wave per 4-row group
// (4 KB contiguous NT streaming). SOFTWARE-PIPELINED: group g+1's loads are
// issued before group g's accumulate, so each wave keeps 8 vf4 loads in
// flight and the predicated-FMA block overlaps the next fetch's latency.
// Wave-uniform bid -> branch-free predicated FMA into vf4 acc[8] (VGPRs).
// Forward order + NT everywhere (R4/R8: cache-policy deviations lose ~10us).
// ---------------------------------------------------------------------------
__global__ __launch_bounds__(256) void pool_kernel(
    const float* __restrict__ x,         // [N, 256]
    const int*   __restrict__ bids,      // [N]
    float*       __restrict__ partials,  // [POOL_BLOCKS][2048]
    float*       __restrict__ cpart,     // [POOL_BLOCKS][8]
    int N)
{
    __shared__ float lsum[4][NB][C];   // 32 KB
    __shared__ float lcnt[4][NB];

    const int tid  = threadIdx.x;
    const int wid  = tid >> 6;
    const int lane = tid & 63;

    vf4   acc[NB];
    float cnt[NB];
    #pragma unroll
    for (int b = 0; b < NB; ++b) { acc[b] = (vf4){0.f,0.f,0.f,0.f}; cnt[b] = 0.f; }

    const int gwave   = blockIdx.x * 4 + wid;
    const int totw    = POOL_BLOCKS * 4;
    const int ngroups = N >> 2;

    int g = gwave;
    if (g < ngroups) {
        size_t r0 = (size_t)g * 4;
        int4 bb = *((const int4*)(bids + r0));
        vf4 v0 = __builtin_nontemporal_load(((const vf4*)(x + (r0 + 0) * C)) + lane);
        vf4 v1 = __builtin_nontemporal_load(((const vf4*)(x + (r0 + 1) * C)) + lane);
        vf4 v2 = __builtin_nontemporal_load(((const vf4*)(x + (r0 + 2) * C)) + lane);
        vf4 v3 = __builtin_nontemporal_load(((const vf4*)(x + (r0 + 3) * C)) + lane);
        while (true) {
            const int gn = g + totw;
            const bool more = (gn < ngroups);
            int4 nb; vf4 n0, n1, n2, n3;
            if (more) {                       // prefetch next group FIRST
                const size_t rn = (size_t)gn * 4;
                nb = *((const int4*)(bids + rn));
                n0 = __builtin_nontemporal_load(((const vf4*)(x + (rn + 0) * C)) + lane);
                n1 = __builtin_nontemporal_load(((const vf4*)(x + (rn + 1) * C)) + lane);
                n2 = __builtin_nontemporal_load(((const vf4*)(x + (rn + 2) * C)) + lane);
                n3 = __builtin_nontemporal_load(((const vf4*)(x + (rn + 3) * C)) + lane);
            }
            const int b0 = __builtin_amdgcn_readfirstlane(bb.x);
            const int b1 = __builtin_amdgcn_readfirstlane(bb.y);
            const int b2 = __builtin_amdgcn_readfirstlane(bb.z);
            const int b3 = __builtin_amdgcn_readfirstlane(bb.w);
            #pragma unroll
            for (int b = 0; b < NB; ++b) {
                const float m0 = (b0 == b) ? 1.f : 0.f;
                const float m1 = (b1 == b) ? 1.f : 0.f;
                const float m2 = (b2 == b) ? 1.f : 0.f;
                const float m3 = (b3 == b) ? 1.f : 0.f;
                acc[b] += v0 * m0;
                acc[b] += v1 * m1;
                acc[b] += v2 * m2;
                acc[b] += v3 * m3;
                cnt[b] += m0 + m1 + m2 + m3;
            }
            if (!more) break;
            bb = nb; v0 = n0; v1 = n1; v2 = n2; v3 = n3; g = gn;
        }
    }
    // leftover rows if N % 4 != 0 (none at N=262144) — wave 0 handles them
    if (gwave == 0) {
        for (int row = ngroups * 4; row < N; ++row) {
            const int bb = __builtin_amdgcn_readfirstlane(bids[row]);
            const vf4 v = ((const vf4*)(x + (size_t)row * C))[lane];
            #pragma unroll
            for (int b = 0; b < NB; ++b) {
                const float m = (bb == b) ? 1.f : 0.f;
                acc[b] += v * m;
                cnt[b] += m;
            }
        }
    }

    // one conflict-free b128 LDS write per batch per lane
    #pragma unroll
    for (int b = 0; b < NB; ++b)
        ((vf4*)&lsum[wid][b][0])[lane] = acc[b];
    if (lane == 0) {
        #pragma unroll
        for (int b = 0; b < NB; ++b) lcnt[wid][b] = cnt[b];
    }
    __syncthreads();

    float* pout = partials + (size_t)blockIdx.x * (NB * C);
    for (int i = tid; i < NB * C; i += 256)
        pout[i] = lsum[0][0][i] + lsum[1][0][i] + lsum[2][0][i] + lsum[3][0][i];
    if (tid < NB)
        cpart[blockIdx.x * NB + tid] =
            lcnt[0][tid] + lcnt[1][tid] + lcnt[2][tid] + lcnt[3][tid];
}

// ---------------------------------------------------------------------------
// Kernel 2: tree-reduce the per-block partials. 64 blocks: blockIdx = jp*8+jo;
// block sums PR partial rows over its 256-col chunk (coalesced 1 KB reads).
// jo==0 blocks also reduce the count partials. (R9 proved 8-block merge is
// latency-bound; 64 blocks stays.)
// ---------------------------------------------------------------------------
__global__ __launch_bounds__(256) void reduce_kernel(
    const float* __restrict__ partials,  // [POOL_BLOCKS][2048]
    const float* __restrict__ cpart,     // [POOL_BLOCKS][8]
    float*       __restrict__ partial2,  // [8][2048]
    float*       __restrict__ c2)        // [8][8]
{
    const int jo  = blockIdx.x & 7;   // column chunk
    const int jp  = blockIdx.x >> 3;  // partial-row chunk
    const int col = jo * 256 + threadIdx.x;
    const int PR  = POOL_BLOCKS / 8;  // 64 rows per jp

    float s = 0.f;
    #pragma unroll 8
    for (int p = 0; p < PR; ++p)
        s += partials[(size_t)(jp * PR + p) * (NB * C) + col];
    partial2[jp * (NB * C) + col] = s;

    if (jo == 0 && threadIdx.x < NB) {
        float c = 0.f;
        for (int p = 0; p < PR; ++p)
            c += cpart[(jp * PR + p) * NB + threadIdx.x];
        c2[jp * NB + threadIdx.x] = c;
    }
}

// ---------------------------------------------------------------------------
// Kernel 3: final reduce + tiny MLP. pooled = sums/max(cnt,1);
// h = relu(pooled@W1+b1); y = sigmoid(h@W2+b2). One block, 256 threads.
// ---------------------------------------------------------------------------
__global__ __launch_bounds__(256) void mlp_kernel(
    const float* __restrict__ partial2,  // [8][2048]
    const float* __restrict__ c2,        // [8][8]
    const float* __restrict__ W1,        // [256][64]
    const float* __restrict__ b1,        // [64]
    const float* __restrict__ W2,        // [64][256]
    const float* __restrict__ b2,        // [256]
    float*       __restrict__ y)         // [8][256] out
{
    __shared__ float pooled[NB][C];
    __shared__ float h[NB][CR];
    __shared__ float cnts[NB];
    const int tid = threadIdx.x;

    if (tid < NB) {
        float c = 0.f;
        #pragma unroll
        for (int j = 0; j < 8; ++j) c += c2[j * NB + tid];
        cnts[tid] = fmaxf(c, 1.f);
    }
    __syncthreads();

    for (int i = tid; i < NB * C; i += 256) {
        float s = 0.f;
        #pragma unroll
        for (int j = 0; j < 8; ++j) s += partial2[j * (NB * C) + i];
        (&pooled[0][0])[i] = s / cnts[i >> 8];
    }
    __syncthreads();

    // h: 8*64 = 512 outputs, 2 per thread
    for (int o = tid; o < NB * CR; o += 256) {
        const int b = o >> 6, j = o & 63;
        float acc = b1[j];
        #pragma unroll 4
        for (int k = 0; k < C; ++k) acc = fmaf(pooled[b][k], W1[k * CR + j], acc);
        (&h[0][0])[o] = fmaxf(acc, 0.f);
    }
    __syncthreads();

    // y: 8*256 = 2048 outputs, 8 per thread
    for (int o = tid; o < NB * C; o += 256) {
        const int b = o >> 8, j = o & 255;
        float acc = b2[j];
        #pragma unroll
        for (int k = 0; k < CR; ++k) acc = fmaf(h[b][k], W2[k * C + j], acc);
        y[o] = 1.f / (1.f + __expf(-acc));
    }
}

// ---------------------------------------------------------------------------
// Kernel 4: out[row,:] = y[bids[row],:] * x[row,:]. One wave per 4-row group,
// SOFTWARE-PIPELINED: group g+1's loads issue before group g's multiply+store,
// so the store phase overlaps the next fetch. FORWARD order, y in LDS
// (uniform bid -> 2-way b128 = free), NT load/store.
// ---------------------------------------------------------------------------
__global__ __launch_bounds__(256) void scale_kernel(
    const float* __restrict__ x,     // [N, 256]
    const int*   __restrict__ bids,  // [N]
    const float* __restrict__ y,     // [8][256]
    float*       __restrict__ out,   // [N, 256]
    int N)
{
    __shared__ float ly[NB][C];      // 8 KB
    const int tid = threadIdx.x;
    for (int i = tid; i < NB * C; i += 256) (&ly[0][0])[i] = y[i];
    __syncthreads();

    const int wid  = tid >> 6;
    const int lane = tid & 63;
    const int gwave   = blockIdx.x * 4 + wid;
    const int totw    = SCALE_BLOCKS * 4;
    const int ngroups = N >> 2;

    int g = gwave;
    if (g < ngroups) {
        size_t r0 = (size_t)g * 4;
        int4 bb = *((const int4*)(bids + r0));
        vf4 v0 = __builtin_nontemporal_load(((const vf4*)(x + (r0 + 0) * C)) + lane);
        vf4 v1 = __builtin_nontemporal_load(((const vf4*)(x + (r0 + 1) * C)) + lane);
        vf4 v2 = __builtin_nontemporal_load(((const vf4*)(x + (r0 + 2) * C)) + lane);
        vf4 v3 = __builtin_nontemporal_load(((const vf4*)(x + (r0 + 3) * C)) + lane);
        while (true) {
            const int gn = g + totw;
            const bool more = (gn < ngroups);
            int4 nb; vf4 n0, n1, n2, n3;
            if (more) {                       // prefetch next group FIRST
                const size_t rn = (size_t)gn * 4;
                nb = *((const int4*)(bids + rn));
                n0 = __builtin_nontemporal_load(((const vf4*)(x + (rn + 0) * C)) + lane);
                n1 = __builtin_nontemporal_load(((const vf4*)(x + (rn + 1) * C)) + lane);
                n2 = __builtin_nontemporal_load(((const vf4*)(x + (rn + 2) * C)) + lane);
                n3 = __builtin_nontemporal_load(((const vf4*)(x + (rn + 3) * C)) + lane);
            }
            const size_t r0c = (size_t)g * 4;
            const int b0 = __builtin_amdgcn_readfirstlane(bb.x);
            const int b1 = __builtin_amdgcn_readfirstlane(bb.y);
            const int b2 = __builtin_amdgcn_readfirstlane(bb.z);
            const int b3 = __builtin_amdgcn_readfirstlane(bb.w);
            const vf4 g0 = ((const vf4*)&ly[b0][0])[lane];
            const vf4 g1 = ((const vf4*)&ly[b1][0])[lane];
            const vf4 g2 = ((const vf4*)&ly[b2][0])[lane];
            const vf4 g3 = ((const vf4*)&ly[b3][0])[lane];
            __builtin_nontemporal_store(v0 * g0, ((vf4*)(out + (r0c + 0) * C)) + lane);
            __builtin_nontemporal_store(v1 * g1, ((vf4*)(out + (r0c + 1) * C)) + lane);
            __builtin_nontemporal_store(v2 * g2, ((vf4*)(out + (r0c + 2) * C)) + lane);
            __builtin_nontemporal_store(v3 * g3, ((vf4*)(out + (r0c + 3) * C)) + lane);
            if (!more) break;
            bb = nb; v0 = n0; v1 = n1; v2 = n2; v3 = n3; g = gn;
        }
    }
    if (gwave == 0) {                 // tail rows if N % 4 != 0
        for (int row = ngroups * 4; row < N; ++row) {
            const int bb = __builtin_amdgcn_readfirstlane(bids[row]);
            const vf4 v  = ((const vf4*)(x + (size_t)row * C))[lane];
            const vf4 gg = ((const vf4*)&ly[bb][0])[lane];
            ((vf4*)(out + (size_t)row * C))[lane] = v * gg;
        }
    }
}

extern "C" void kernel_launch(void* const* d_in, const int* in_sizes, int n_in,
                              void* d_out, int out_size, void* d_ws, size_t ws_size,
                              hipStream_t stream)
{
    const float* x    = (const float*)d_in[0];
    const int*   bids = (const int*)  d_in[1];
    const float* W1   = (const float*)d_in[2];
    const float* b1   = (const float*)d_in[3];
    const float* W2   = (const float*)d_in[4];
    const float* b2   = (const float*)d_in[5];
    float* out = (float*)d_out;

    const int N = in_sizes[1];           // 262144

    // ws layout (floats), all regions fully written before read each call:
    // partials[512*2048] | cpart[512*8] | partial2[8*2048] | c2[64] | gy[2048]
    float* partials = (float*)d_ws;
    float* cpart    = partials + POOL_BLOCKS * (NB * C);
    float* partial2 = cpart + POOL_BLOCKS * NB;
    float* c2       = partial2 + 8 * (NB * C);
    float* gy       = c2 + 64;

    pool_kernel  <<<POOL_BLOCKS, 256, 0, stream>>>(x, bids, partials, cpart, N);
    reduce_kernel<<<64, 256, 0, stream>>>(partials, cpart, partial2, c2);
    mlp_kernel   <<<1, 256, 0, stream>>>(partial2, c2, W1, b1, W2, b2, gy);
    scale_kernel <<<SCALE_BLOCKS, 256, 0, stream>>>(x, bids, gy, out, N);
}